// Round 2
// 196.631 us; speedup vs baseline: 1.1120x; 1.1120x over previous
//
#include <hip/hip_runtime.h>
#include <hip/hip_bf16.h>

#define DIMK 3
#define NPTS 30
#define KK   181
#define PP   24360
#define DEMB 190
#define VLD  192   // padded vec row stride (bf16 elements)
#define SNP  24576 // padded row length = 16*1536 (sort rows AND sm2T stride)

typedef __attribute__((ext_vector_type(8))) short bf16x8;
typedef __attribute__((ext_vector_type(4))) float f32x4;
typedef __attribute__((ext_vector_type(2))) __fp16 h2;

__device__ __forceinline__ ushort f2bf(float f) {
    unsigned u = __float_as_uint(f);
    u += 0x7FFFu + ((u >> 16) & 1u);
    return (ushort)(u >> 16);
}

// ---------------------------------------------------------------------------
// Kernel 1: per-permutation inner embed -> vec (PP x VLD, bf16)
// Round-23: packed-f16 PAIR sorting (r22 fixed: h2 must be __fp16-based to
// match __builtin_amdgcn_cvt_pkrtz's return type). Each lane processes two
// consecutive permutations (p0=2t, p1=2t+1), one value per f16 half; the
// Batcher network runs on v_pk_min_f16/v_pk_max_f16 so each comparator
// serves TWO sorts. Since 812 and 28 are even, p0/p1 always share (i0,i1)
// -> c0,c1 identical, only c2 differs: one decode, shared w0*g0+w1*g1
// partial per element. Network pruned: positions 30,31 are INF forever (13
// comparators with b>=30 are no-ops) and outputs 27..29 are don't-care
// ((27,28),(27,29) in the last merge pruned) -> 176 comparators, 30-register
// sort array. Dot accumulates in f32 via (float)h * w (v_fma_mix). f16
// (10-bit mantissa) error is below the bf16 (8-bit) quantization already
// applied to emb and to the outer 16-bit sort keys.
// ---------------------------------------------------------------------------
__global__ __launch_bounds__(1024, 2) void k_inner(
    const float* __restrict__ M,      // 3 x 30
    const float* __restrict__ Ws_in,  // 181 x 3
    const float* __restrict__ Wd_in,  // 181 x 27
    const float* __restrict__ Wout,   // 181 x 190
    ushort* __restrict__ Abf,         // 192 x 192 bf16 out
    ushort* __restrict__ vec)         // PP x VLD (bf16)
{
    __shared__ float Gs[NPTS * 32];
    __shared__ float WsS[192 * 3];
    __shared__ float WdS[192 * 28];

    const int tid = threadIdx.x;

    {
        int gid = blockIdx.x * 1024 + tid;
        if (gid < 192 * 192) {
            int k = gid / 192, d = gid - k * 192;
            Abf[gid] = (k < KK && d < DEMB) ? f2bf(Wout[k * DEMB + d]) : (ushort)0;
        }
    }

    for (int i = tid; i < 192 * 3; i += 1024) WsS[i] = (i < KK * 3) ? Ws_in[i] : 0.f;
    for (int i = tid; i < 192 * 28; i += 1024) {
        int k = i / 28, m = i - k * 28;
        WdS[i] = (k < KK && m < 27) ? Wd_in[k * 27 + m] : 0.f;
    }
    for (int e = tid; e < NPTS * 32; e += 1024) {
        int a = e >> 5, b = e & 31;
        Gs[e] = (b < NPTS)
            ? (M[a] * M[b] + M[NPTS + a] * M[NPTS + b] + M[2 * NPTS + a] * M[2 * NPTS + b])
            : 0.f;
    }
    __syncthreads();

    const int wave = tid >> 6;
    const int lane = tid & 63;
    const int wid = blockIdx.x * 16 + wave;   // 0..8191
    const int chunk = wid % 3;
    const int pstream = wid / 3;              // 0..2730
    const int nstream = (chunk == 2) ? 2730 : 2731;
    const int k = chunk * 64 + lane;

    const float INF = __builtin_inff();
    const bool kvalid = (k < KK);
    const float w0 = WsS[k * 3 + 0];
    const float w1 = WsS[k * 3 + 1];
    const float w2 = WsS[k * 3 + 2];
    const float* wd = WdS + k * 28;

    const int NPAIR = PP / 2;   // 12180

    for (int t = pstream; t < NPAIR; t += nstream) {
        const int p0 = 2 * t;
        // decode p0; p1 = p0+1 always shares i0,i1 (i2 of p0 is even, <=26)
        int i0 = p0 / 812;            // 812 = 29*28
        int r  = p0 - i0 * 812;
        int i1 = r / 28;
        int i2 = r - i1 * 28;
        int c0 = i0;
        int c1 = i1 + (i1 >= c0 ? 1 : 0);
        int lo = min(c0, c1), hi = max(c0, c1);
        int c2a = i2;
        if (c2a >= lo) c2a++;
        if (c2a >= hi) c2a++;
        int c2b = i2 + 1;
        if (c2b >= lo) c2b++;
        if (c2b >= hi) c2b++;

        ushort* vrow0 = vec + (long)p0 * VLD;
        ushort* vrow1 = vrow0 + VLD;

        if (chunk == 0 && lane < 9) {
            int i = lane / 3, j = lane % 3;
            int cia = (i == 0) ? c0 : ((i == 1) ? c1 : c2a);
            int cja = (j == 0) ? c0 : ((j == 1) ? c1 : c2a);
            vrow0[lane] = f2bf(Gs[(cia << 5) + cja]);
            int cib = (i == 0) ? c0 : ((i == 1) ? c1 : c2b);
            int cjb = (j == 0) ? c0 : ((j == 1) ? c1 : c2b);
            vrow1[lane] = f2bf(Gs[(cib << 5) + cjb]);
        }

        const float* g0 = Gs + (c0 << 5);
        const float* g1 = Gs + (c1 << 5);
        const float* ga = Gs + (c2a << 5);
        const float* gb = Gs + (c2b << 5);
        const unsigned basem = (1u << c0) | (1u << c1);
        const unsigned maska = basem | (1u << c2a);
        const unsigned maskb = basem | (1u << c2b);

        h2 s[30];
#pragma unroll
        for (int q = 0; q < 8; ++q) {
            float4 x0 = *(const float4*)&g0[q * 4];
            float4 x1 = *(const float4*)&g1[q * 4];
            float4 xa = *(const float4*)&ga[q * 4];
            float4 xb = *(const float4*)&gb[q * 4];
            int j0 = q * 4;
            if (j0 + 0 < NPTS) {
                float c = w0 * x0.x + w1 * x1.x;
                float va = w2 * xa.x + c;
                float vb = w2 * xb.x + c;
                va = ((maska >> (j0 + 0)) & 1u) ? INF : va;
                vb = ((maskb >> (j0 + 0)) & 1u) ? INF : vb;
                s[j0 + 0] = __builtin_amdgcn_cvt_pkrtz(va, vb);
            }
            if (j0 + 1 < NPTS) {
                float c = w0 * x0.y + w1 * x1.y;
                float va = w2 * xa.y + c;
                float vb = w2 * xb.y + c;
                va = ((maska >> (j0 + 1)) & 1u) ? INF : va;
                vb = ((maskb >> (j0 + 1)) & 1u) ? INF : vb;
                s[j0 + 1] = __builtin_amdgcn_cvt_pkrtz(va, vb);
            }
            if (j0 + 2 < NPTS) {
                float c = w0 * x0.z + w1 * x1.z;
                float va = w2 * xa.z + c;
                float vb = w2 * xb.z + c;
                va = ((maska >> (j0 + 2)) & 1u) ? INF : va;
                vb = ((maskb >> (j0 + 2)) & 1u) ? INF : vb;
                s[j0 + 2] = __builtin_amdgcn_cvt_pkrtz(va, vb);
            }
            if (j0 + 3 < NPTS) {
                float c = w0 * x0.w + w1 * x1.w;
                float va = w2 * xa.w + c;
                float vb = w2 * xb.w + c;
                va = ((maska >> (j0 + 3)) & 1u) ? INF : va;
                vb = ((maskb >> (j0 + 3)) & 1u) ? INF : vb;
                s[j0 + 3] = __builtin_amdgcn_cvt_pkrtz(va, vb);
            }
        }

        // Batcher odd-even mergesort, 32-wire network on wires 0..29,
        // pruned: b>=30 are no-ops (wires 30,31 = +INF forever);
        // (27,28)@pw16/kk1 and (27,29)@pw16/kk2 only feed don't-care outputs.
        // Packed: each comparator sorts both p0 (lo) and p1 (hi) halves.
#pragma unroll
        for (int pw = 1; pw < 32; pw <<= 1) {
#pragma unroll
            for (int kk = pw; kk >= 1; kk >>= 1) {
#pragma unroll
                for (int j = kk % pw; j + kk < 32; j += 2 * kk) {
#pragma unroll
                    for (int i = 0; i < kk; ++i) {
                        int a = i + j, b = i + j + kk;
                        if (a / (pw * 2) == b / (pw * 2) && b < 30
                            && !(pw == 16 && a == 27)) {
                            h2 x = s[a], y = s[b];
                            s[a] = __builtin_elementwise_min(x, y);
                            s[b] = __builtin_elementwise_max(x, y);
                        }
                    }
                }
            }
        }

        if (kvalid) {
            float emb0 = 0.f, emb1 = 0.f;
#pragma unroll
            for (int j = 0; j < 24; j += 4) {
                float4 w4 = *(const float4*)&wd[j];
                emb0 += w4.x * (float)s[j + 0].x + w4.y * (float)s[j + 1].x
                      + w4.z * (float)s[j + 2].x + w4.w * (float)s[j + 3].x;
                emb1 += w4.x * (float)s[j + 0].y + w4.y * (float)s[j + 1].y
                      + w4.z * (float)s[j + 2].y + w4.w * (float)s[j + 3].y;
            }
            {
                float4 w4 = *(const float4*)&wd[24];   // wd[27] exists (=0), unused
                emb0 += w4.x * (float)s[24].x + w4.y * (float)s[25].x
                      + w4.z * (float)s[26].x;
                emb1 += w4.x * (float)s[24].y + w4.y * (float)s[25].y
                      + w4.z * (float)s[26].y;
            }
            vrow0[9 + k] = f2bf(emb0);
            vrow1[9 + k] = f2bf(emb1);
        } else if (k < 183) {
            vrow0[9 + k] = 0;
            vrow1[9 + k] = 0;
        }
    }
}

// ---------------------------------------------------------------------------
// Kernel 2: sm2TP[k][p] via bf16 MFMA, no LDS, 16-bit encoded-key stores,
// kt quarters (3 kt/block, grid 1536) [frozen, r20]
// ---------------------------------------------------------------------------
__global__ __launch_bounds__(256) void k_gemm(
    const ushort* __restrict__ vecB,  // PP x 192 bf16
    const ushort* __restrict__ Abf,   // 192 x 192 bf16
    ushort* __restrict__ sm2TP)       // 181 x SNP u16 encoded keys
{
    const int tid  = threadIdx.x;
    const int bid  = blockIdx.x;
    const int tile = bid >> 2;        // p-tile (64 p's)
    const int qtr  = bid & 3;         // kt quarter: 3 kt each
    const int wave = tid >> 6;
    const int lane = tid & 63;
    const int n = lane & 15;
    const int quad = lane >> 4;
    const int p = tile * 64 + wave * 16 + n;   // < SNP by grid construction

    bf16x8 bfrag[6];
    if (p < PP) {
        const ushort* row = vecB + (long)p * VLD;
#pragma unroll
        for (int kc = 0; kc < 6; ++kc)
            bfrag[kc] = *(const bf16x8*)&row[kc * 32 + quad * 8];
    } else {
        bf16x8 z = {0, 0, 0, 0, 0, 0, 0, 0};
#pragma unroll
        for (int kc = 0; kc < 6; ++kc) bfrag[kc] = z;
    }

#pragma unroll
    for (int i = 0; i < 3; ++i) {
        const int kt = qtr * 3 + i;
        f32x4 acc = {0.f, 0.f, 0.f, 0.f};
        const ushort* arow = Abf + (kt * 16 + n) * 192;
#pragma unroll
        for (int kc = 0; kc < 6; ++kc) {
            bf16x8 afrag = *(const bf16x8*)&arow[kc * 32 + quad * 8];
            acc = __builtin_amdgcn_mfma_f32_16x16x32_bf16(afrag, bfrag[kc], acc, 0, 0, 0);
        }
        int k0 = kt * 16 + quad * 4;
#pragma unroll
        for (int r = 0; r < 4; ++r) {
            int kg = k0 + r;
            if (kg < KK) {
                unsigned e;
                if (p < PP) {
                    unsigned u = __float_as_uint(acc[r]);
                    u = (u & 0x80000000u) ? ~u : (u | 0x80000000u);
                    e = (u + 0x8000u) >> 16;     // RTN 16-bit monotone key
                } else {
                    e = 0xFFFFu;                 // pad sorts strictly last
                }
                sm2TP[(long)kg * SNP + p] = (ushort)e;
            }
        }
    }
}

// ---------------------------------------------------------------------------
// Kernel 3: per-k radix sort on 16-bit keys, 2 x 8-bit passes, 3 traversals,
// no global intermediate [frozen, r19].
// ---------------------------------------------------------------------------
#define WAVES  16
#define WCHUNK 1536

__device__ __forceinline__ unsigned long long matchany8(unsigned d) {
    unsigned long long m = ~0ull;
#pragma unroll
    for (int b = 0; b < 8; ++b) {
        unsigned bit = (d >> b) & 1u;
        unsigned long long bal = __ballot(bit);
        m &= bit ? bal : ~bal;
    }
    return m;
}

__device__ __forceinline__ void scan_hist(unsigned* cntC, unsigned* cntZ,
                                          unsigned* tot, int tid) {
    if (tid < 256) {
        unsigned run = 0;
        for (int w = 0; w < WAVES; ++w) {
            unsigned t = cntC[w * 256 + tid];
            cntC[w * 256 + tid] = run;
            run += t;
        }
        tot[tid] = run;
    }
    __syncthreads();
    if (tid < 64) {
        unsigned t0 = tot[tid * 4], t1 = tot[tid * 4 + 1];
        unsigned t2 = tot[tid * 4 + 2], t3 = tot[tid * 4 + 3];
        unsigned s = t0 + t1 + t2 + t3;
        unsigned sc = s;
#pragma unroll
        for (int off = 1; off < 64; off <<= 1) {
            unsigned o = (unsigned)__shfl_up((int)sc, off, 64);
            if (tid >= off) sc += o;
        }
        unsigned ex = sc - s;
        tot[tid * 4]     = ex + t0;
        tot[tid * 4 + 1] = ex + t0 + t1;
        tot[tid * 4 + 2] = ex + t0 + t1 + t2;
        tot[tid * 4 + 3] = ex + s;
    } else if (cntZ) {
        for (int i = tid - 64; i < WAVES * 256; i += 1024 - 64) cntZ[i] = 0;
    }
    __syncthreads();
    for (int i = tid; i < WAVES * 256; i += 1024) {
        int d = i & 255;
        unsigned db = (d == 0) ? 0u : tot[d - 1];
        cntC[i] += db;
    }
    __syncthreads();
}

__global__ __launch_bounds__(1024) void k_sort(
    const ushort* __restrict__ sm2TP,    // 181 x SNP u16 keys (padded)
    const float* __restrict__ WdOut,     // 181 x PP
    float* __restrict__ out)             // 181
{
    __shared__ ushort keysL[SNP];           // 48 KiB
    __shared__ unsigned cntA[WAVES * 256];  // 16 KiB
    __shared__ unsigned cntB[WAVES * 256];  // 16 KiB
    __shared__ unsigned tot[256];
    __shared__ float red[WAVES];

    const int tid  = threadIdx.x;
    const int wave = tid >> 6;
    const int lane = tid & 63;
    const int k    = blockIdx.x;

    const ushort* rowU = sm2TP + (long)k * SNP;
    const float* wrow  = WdOut + (long)k * PP;

    const int base_idx = wave * WCHUNK + lane;
    const int wbase = wave * 256;
    const unsigned long long lt_mask = (1ull << lane) - 1ull;

    for (int i = tid; i < WAVES * 256; i += 1024) cntA[i] = 0;
    __syncthreads();

    // ---- count0: low byte, uniform over SNP ----
    for (int j = 0; j < 24; ++j) {
        unsigned u = rowU[base_idx + j * 64];
        atomicAdd(&cntA[wbase + (u & 255u)], 1u);
    }
    __syncthreads();
    scan_hist(cntA, cntB, tot, tid);   // also zeroes cntB

    // ---- scatter0: G -> LDS on low byte, fused count1 (high byte) ----
    for (int j = 0; j < 24; ++j) {
        unsigned u = rowU[base_idx + j * 64];
        unsigned d = u & 255u;
        unsigned long long mm = matchany8(d);
        int leader = __ffsll(mm) - 1;
        unsigned myrank = (unsigned)__popcll(mm & lt_mask);
        unsigned old = 0;
        if (lane == leader)
            old = atomicAdd(&cntA[wbase + d], (unsigned)__popcll(mm));
        old = (unsigned)__shfl((int)old, leader, 64);
        unsigned dest = old + myrank;
        keysL[dest] = (ushort)u;
        atomicAdd(&cntB[(dest / WCHUNK) * 256 + (u >> 8)], 1u);
    }
    __syncthreads();
    scan_hist(cntB, (unsigned*)0, tot, tid);

    // ---- scatter1: LDS -> fused dot on high byte (pads -> dest >= PP) ----
    float local = 0.f;
    for (int j = 0; j < 24; ++j) {
        unsigned u = keysL[base_idx + j * 64];
        unsigned d = u >> 8;
        unsigned long long mm = matchany8(d);
        int leader = __ffsll(mm) - 1;
        unsigned myrank = (unsigned)__popcll(mm & lt_mask);
        unsigned old = 0;
        if (lane == leader)
            old = atomicAdd(&cntB[wbase + d], (unsigned)__popcll(mm));
        old = (unsigned)__shfl((int)old, leader, 64);
        unsigned dest = old + myrank;
        if (dest < PP) {
            unsigned raw16 = (u & 0x8000u) ? (u & 0x7FFFu) : ((~u) & 0xFFFFu);
            local += wrow[dest] * __uint_as_float(raw16 << 16);
        }
    }

#pragma unroll
    for (int off = 32; off > 0; off >>= 1)
        local += __shfl_down(local, off, 64);
    if (lane == 0) red[wave] = local;
    __syncthreads();
    if (tid < WAVES) {
        float x = red[tid];
#pragma unroll
        for (int off = 8; off > 0; off >>= 1)
            x += __shfl_down(x, off, 64);
        if (tid == 0) out[k] = x;
    }
}

// ---------------------------------------------------------------------------
extern "C" void kernel_launch(void* const* d_in, const int* in_sizes, int n_in,
                              void* d_out, int out_size, void* d_ws, size_t ws_size,
                              hipStream_t stream) {
    const float* M      = (const float*)d_in[0];
    const float* Ws_in  = (const float*)d_in[1];
    const float* Wd_in  = (const float*)d_in[2];
    const float* Ws_out = (const float*)d_in[3];
    const float* Wd_out = (const float*)d_in[4];
    float* out = (float*)d_out;

    // workspace layout (18.4 MB):
    // [0, 9.36 MB):    vecB (PP x 192 bf16)
    // [9.36, 18.26):   sm2TP (181 x SNP u16 keys)
    // [18.26, +74KB):  Abf (192 x 192 bf16)
    char* ws = (char*)d_ws;
    ushort* vecB  = (ushort*)ws;
    ushort* sm2TP = (ushort*)(ws + (size_t)PP * VLD * 2);
    ushort* Abf   = (ushort*)(ws + (size_t)PP * VLD * 2 + (size_t)KK * SNP * 2);

    k_inner<<<512, 1024, 0, stream>>>(M, Ws_in, Wd_in, Ws_out, Abf, vecB);

    k_gemm<<<(SNP / 64) * 4, 256, 0, stream>>>(vecB, Abf, sm2TP);

    k_sort<<<KK, 1024, 0, stream>>>(sm2TP, Wd_out, out);
}